// Round 1
// baseline (1511.468 us; speedup 1.0000x reference)
//
#include <hip/hip_runtime.h>
#include <cstdint>
#include <cstddef>

typedef unsigned short u16;
typedef __bf16 bf16x8 __attribute__((ext_vector_type(8)));
typedef float f32x4 __attribute__((ext_vector_type(4)));

#define GLD16(gp, lp) __builtin_amdgcn_global_load_lds( \
    (const __attribute__((address_space(1))) void*)(gp), \
    (__attribute__((address_space(3))) void*)(lp), 16, 0, 0)

static constexpr int kNT  = 217;   // tokens per batch item
static constexpr int kM   = 1736;  // 8 * 217 valid rows
static constexpr int kMp  = 1792;  // padded to 14*128
static constexpr int kHid = 768;

__device__ __forceinline__ u16 f2bf(float f) {
    union { float f; unsigned u; } x; x.f = f;
    unsigned r = x.u + 0x7fffu + ((x.u >> 16) & 1u);
    return (u16)(r >> 16);
}

// ---------------- im2col: img (8,4,96,96,96) f32 -> A (1792 x 16384) bf16 -----
// row m = b*216 + p (p = pd*36+ph*6+pw), col k = c*4096 + i*256 + j*16 + kk
__global__ void im2col_kernel(const float* __restrict__ img, u16* __restrict__ A) {
    int t = blockIdx.x * 256 + threadIdx.x;      // 1,769,472 threads, 16 elems each
    int m  = t >> 10;                             // /1024 (16-elem blocks per row)
    int kb = t & 1023;
    int c = kb >> 8;
    int i = (kb >> 4) & 15;
    int j = kb & 15;
    int b = m / 216, p = m % 216;
    int pd = p / 36, ph = (p / 6) % 6, pw = p % 6;
    const float* src = img + ((((size_t)(b * 4 + c) * 96 + pd * 16 + i) * 96 + (ph * 16 + j)) * 96 + pw * 16);
    u16* dst = A + (size_t)m * 16384 + (size_t)kb * 16;
    #pragma unroll
    for (int q = 0; q < 16; q += 4) {
        float4 v = *(const float4*)(src + q);
        dst[q + 0] = f2bf(v.x); dst[q + 1] = f2bf(v.y);
        dst[q + 2] = f2bf(v.z); dst[q + 3] = f2bf(v.w);
    }
}

// ---------------- straight f32 -> bf16 convert (conv_w: already N x K layout) --
__global__ void cvt_kernel(const float* __restrict__ src, u16* __restrict__ dst) {
    size_t i = ((size_t)blockIdx.x * 256 + threadIdx.x) * 4;
    float4 v = *(const float4*)(src + i);
    dst[i + 0] = f2bf(v.x); dst[i + 1] = f2bf(v.y);
    dst[i + 2] = f2bf(v.z); dst[i + 3] = f2bf(v.w);
}

// ---------------- transpose + convert: src (R x C) f32 -> dst (C x R) bf16 ----
__global__ void transcvt(const float* __restrict__ src0, u16* __restrict__ dst0, int R, int C) {
    const float* src = src0 + (size_t)blockIdx.z * R * C;
    u16*         dst = dst0 + (size_t)blockIdx.z * R * C;
    __shared__ float tl[32][33];
    int c0 = blockIdx.x * 32, r0 = blockIdx.y * 32;
    for (int rr = threadIdx.y; rr < 32; rr += 8)
        tl[rr][threadIdx.x] = src[(size_t)(r0 + rr) * C + c0 + threadIdx.x];
    __syncthreads();
    for (int rr = threadIdx.y; rr < 32; rr += 8)
        dst[(size_t)(c0 + rr) * R + r0 + threadIdx.x] = f2bf(tl[threadIdx.x][rr]);
}

// ---------------- token0: clin @ ehr_w + ehr_b + pos_emb[0] -> x row b*217 ----
__global__ void token0_kernel(const float* __restrict__ clin, const float* __restrict__ ehr_w,
                              const float* __restrict__ ehr_b, const float* __restrict__ pos,
                              float* __restrict__ x) {
    int b = blockIdx.x;
    for (int o = threadIdx.x; o < 768; o += 256) {
        float acc = ehr_b[o] + pos[o];
        #pragma unroll
        for (int k = 0; k < 16; ++k) acc += clin[b * 16 + k] * ehr_w[k * 768 + o];
        x[(size_t)(b * kNT) * 768 + o] = acc;
    }
}

// ---------------- LayerNorm: x f32 (row) -> bf16 normalized ------------------
__global__ __launch_bounds__(256) void ln_kernel(const float* __restrict__ x,
                                                 const float* __restrict__ w,
                                                 const float* __restrict__ b,
                                                 u16* __restrict__ out) {
    int row = blockIdx.x;
    const float* xr = x + (size_t)row * 768;
    int tid = threadIdx.x;
    float v0 = xr[tid], v1 = xr[tid + 256], v2 = xr[tid + 512];
    float s = v0 + v1 + v2;
    float s2 = v0 * v0 + v1 * v1 + v2 * v2;
    #pragma unroll
    for (int o = 32; o; o >>= 1) { s += __shfl_xor(s, o); s2 += __shfl_xor(s2, o); }
    __shared__ float ps[4], ps2[4];
    int wave = tid >> 6, lane = tid & 63;
    if (lane == 0) { ps[wave] = s; ps2[wave] = s2; }
    __syncthreads();
    s = ps[0] + ps[1] + ps[2] + ps[3];
    s2 = ps2[0] + ps2[1] + ps2[2] + ps2[3];
    float mean = s * (1.0f / 768.0f);
    float var = s2 * (1.0f / 768.0f) - mean * mean;
    float rstd = rsqrtf(var + 1e-5f);
    u16* orow = out + (size_t)row * 768;
    orow[tid]       = f2bf((v0 - mean) * rstd * w[tid]       + b[tid]);
    orow[tid + 256] = f2bf((v1 - mean) * rstd * w[tid + 256] + b[tid + 256]);
    orow[tid + 512] = f2bf((v2 - mean) * rstd * w[tid + 512] + b[tid + 512]);
}

// ---------------- MFMA GEMM: C = A(MxK,bf16) * B^T(NxK,bf16), 128x128 tile ----
// EPI 0: patch embed -> x[(b*217+1+p)*768+col] = c + conv_b[col] + pos[(1+p)*768+col]
// EPI 1: qkv -> qkvb[row*2304+col] = c * (col<768 ? 0.125 : 1)
// EPI 2: ff1 -> gbuf[row*768+col] = bf16(gelu(c + e0[col]))
// EPI 3: ff2 -> x[row*768+col] += c + e0[col]
template <int EPI>
__global__ void __launch_bounds__(256, 2)
gemm_bt(const u16* __restrict__ A, const u16* __restrict__ B, int K,
        float* __restrict__ Cf, const float* __restrict__ e0,
        const float* __restrict__ e1, u16* __restrict__ Cb, int Mvalid) {
    const int tid = threadIdx.x;
    const int lane = tid & 63;
    const int wave = tid >> 6;
    const int wm = wave >> 1, wn = wave & 1;
    const int bm = blockIdx.y * 128, bn = blockIdx.x * 128;

    __shared__ u16 As[128 * 32];
    __shared__ u16 Bs[128 * 32];

    f32x4 acc[4][4] = {};

    const int ar = tid >> 2;          // 0..63
    const int ak = (tid & 3) * 8;
    const u16* Ag = A + (size_t)(bm + ar) * K + ak;
    const u16* Bg = B + (size_t)(bn + ar) * K + ak;
    u16* AsB = &As[tid * 8];
    u16* BsB = &Bs[tid * 8];
    const size_t rowStep = (size_t)64 * K;

    const int kl = (lane >> 4) * 8;
    const int rl = lane & 15;

    for (int k0 = 0; k0 < K; k0 += 32) {
        GLD16(Ag + k0, AsB);
        GLD16(Ag + k0 + rowStep, AsB + 2048);
        GLD16(Bg + k0, BsB);
        GLD16(Bg + k0 + rowStep, BsB + 2048);
        __syncthreads();
        bf16x8 af[4], bfr[4];
        #pragma unroll
        for (int i = 0; i < 4; ++i) {
            af[i]  = *(const bf16x8*)&As[(wm * 64 + i * 16 + rl) * 32 + kl];
            bfr[i] = *(const bf16x8*)&Bs[(wn * 64 + i * 16 + rl) * 32 + kl];
        }
        #pragma unroll
        for (int i = 0; i < 4; ++i)
            #pragma unroll
            for (int j = 0; j < 4; ++j)
                acc[i][j] = __builtin_amdgcn_mfma_f32_16x16x32_bf16(af[i], bfr[j], acc[i][j], 0, 0, 0);
        __syncthreads();
    }

    const int rl4 = (lane >> 4) * 4;
    const int cl = lane & 15;
    #pragma unroll
    for (int i = 0; i < 4; ++i) {
        #pragma unroll
        for (int j = 0; j < 4; ++j) {
            const int col = bn + wn * 64 + j * 16 + cl;
            #pragma unroll
            for (int r = 0; r < 4; ++r) {
                const int row = bm + wm * 64 + i * 16 + rl4 + r;
                if (row >= Mvalid) continue;
                float v = acc[i][j][r];
                if (EPI == 0) {
                    int b = row / 216, p = row % 216;
                    Cf[(size_t)(b * kNT + 1 + p) * 768 + col] = v + e0[col] + e1[(size_t)(1 + p) * 768 + col];
                } else if (EPI == 1) {
                    Cf[(size_t)row * 2304 + col] = (col < 768) ? v * 0.125f : v;
                } else if (EPI == 2) {
                    float t = v + e0[col];
                    float g = 0.5f * t * (1.0f + erff(t * 0.70710678118654752f));
                    Cb[(size_t)row * 768 + col] = f2bf(g);
                } else {
                    Cf[(size_t)row * 768 + col] += v + e0[col];
                }
            }
        }
    }
}

// ---------------- attention (per (b,h) block): softmax token0 + bcast + dwconv
__global__ __launch_bounds__(256) void attn_kernel(const float* __restrict__ qkv,
                                                   const float* __restrict__ resw_l,
                                                   float* __restrict__ x) {
    const int b = blockIdx.x / 12;
    const int h = blockIdx.x % 12;
    const int tid = threadIdx.x;
    const int wave = tid >> 6, lane = tid & 63;

    __shared__ float vs[217 * 64];
    __shared__ float sc[224];
    __shared__ float outp[64];
    __shared__ float rw[33];

    const size_t base = (size_t)(b * kNT) * 2304 + h * 64;

    for (int i = tid; i < 217 * 64; i += 256) {
        int n = i >> 6, d = i & 63;
        vs[i] = qkv[base + (size_t)n * 2304 + 1536 + d];
    }
    if (tid < 33) rw[tid] = resw_l[h * 33 + tid];

    // scores s_j = qp . k_j (qp already scaled by 1/8)
    float qp = qkv[base + lane];
    for (int j = wave; j < 217; j += 4) {
        float p = qp * qkv[base + (size_t)j * 2304 + 768 + lane];
        #pragma unroll
        for (int o = 32; o; o >>= 1) p += __shfl_xor(p, o);
        if (lane == 0) sc[j] = p;
    }
    __syncthreads();

    if (wave == 0) {
        float sv[4], e[4];
        float m = -1e30f;
        #pragma unroll
        for (int q = 0; q < 4; ++q) {
            int j = lane + q * 64;
            sv[q] = (j < 217) ? sc[j] : -1e30f;
            m = fmaxf(m, sv[q]);
        }
        #pragma unroll
        for (int o = 32; o; o >>= 1) m = fmaxf(m, __shfl_xor(m, o));
        float s = 0.0f;
        #pragma unroll
        for (int q = 0; q < 4; ++q) {
            int j = lane + q * 64;
            e[q] = (j < 217) ? expf(sv[q] - m) : 0.0f;
            s += e[q];
        }
        #pragma unroll
        for (int o = 32; o; o >>= 1) s += __shfl_xor(s, o);
        float inv = 1.0f / s;
        #pragma unroll
        for (int q = 0; q < 4; ++q) {
            int j = lane + q * 64;
            if (j < 217) sc[j] = e[q] * inv;
        }
    }
    __syncthreads();
    if (wave == 0) {
        float acc = 0.0f;
        for (int j = 0; j < 217; ++j) acc += sc[j] * vs[j * 64 + lane];
        outp[lane] = acc;
    }
    __syncthreads();

    const size_t xbase = (size_t)(b * kNT) * 768 + h * 64;
    for (int i = tid; i < 217 * 64; i += 256) {
        int n = i >> 6, d = i & 63;
        float bv = (n == 0) ? outp[d] : vs[d];
        float r = 0.0f;
        #pragma unroll
        for (int t = 0; t < 33; ++t) {
            int idx = n + t - 16;
            if (idx >= 0 && idx < 217) r += rw[t] * vs[idx * 64 + d];
        }
        x[xbase + (size_t)n * 768 + d] += bv + r;
    }
}

extern "C" void kernel_launch(void* const* d_in, const int* in_sizes, int n_in,
                              void* d_out, int out_size, void* d_ws, size_t ws_size,
                              hipStream_t stream) {
    const float* img    = (const float*)d_in[0];
    const float* clin   = (const float*)d_in[1];
    const float* conv_w = (const float*)d_in[2];
    const float* conv_b = (const float*)d_in[3];
    const float* ehr_w  = (const float*)d_in[4];
    const float* ehr_b  = (const float*)d_in[5];
    const float* pos    = (const float*)d_in[6];
    const float* ln_w   = (const float*)d_in[7];
    const float* ln_b   = (const float*)d_in[8];
    const float* qkv_w  = (const float*)d_in[9];
    const float* res_w  = (const float*)d_in[10];
    const float* ffln_w = (const float*)d_in[11];
    const float* ffln_b = (const float*)d_in[12];
    const float* w1     = (const float*)d_in[13];
    const float* b1     = (const float*)d_in[14];
    const float* w2     = (const float*)d_in[15];
    const float* b2     = (const float*)d_in[16];
    float* x = (float*)d_out;   // activations live directly in d_out (8*217*768 f32)

    char* ws = (char*)d_ws;     // ~130 MB total
    u16* A_im  = (u16*)ws;  ws += (size_t)kMp * 16384 * 2;
    u16* Bconv = (u16*)ws;  ws += (size_t)768 * 16384 * 2;
    u16* qkvT  = (u16*)ws;  ws += (size_t)4 * 2304 * 768 * 2;
    u16* w1T   = (u16*)ws;  ws += (size_t)4 * 768 * 768 * 2;
    u16* w2T   = (u16*)ws;  ws += (size_t)4 * 768 * 768 * 2;
    u16* lnbuf = (u16*)ws;  ws += (size_t)kMp * 768 * 2;
    u16* gbuf  = (u16*)ws;  ws += (size_t)kMp * 768 * 2;
    float* qkvb = (float*)ws;  ws += (size_t)kMp * 2304 * 4;

    im2col_kernel<<<6912, 256, 0, stream>>>(img, A_im);
    cvt_kernel<<<12288, 256, 0, stream>>>(conv_w, Bconv);
    transcvt<<<dim3(72, 24, 4), dim3(32, 8), 0, stream>>>(qkv_w, qkvT, 768, 2304);
    transcvt<<<dim3(24, 24, 4), dim3(32, 8), 0, stream>>>(w1, w1T, 768, 768);
    transcvt<<<dim3(24, 24, 4), dim3(32, 8), 0, stream>>>(w2, w2T, 768, 768);
    token0_kernel<<<8, 256, 0, stream>>>(clin, ehr_w, ehr_b, pos, x);
    gemm_bt<0><<<dim3(6, 14), 256, 0, stream>>>(A_im, Bconv, 16384, x, conv_b, pos, nullptr, 1728);

    for (int l = 0; l < 4; ++l) {
        ln_kernel<<<kM, 256, 0, stream>>>(x, ln_w + l * 768, ln_b + l * 768, lnbuf);
        gemm_bt<1><<<dim3(18, 14), 256, 0, stream>>>(lnbuf, qkvT + (size_t)l * 2304 * 768, 768,
                                                     qkvb, nullptr, nullptr, nullptr, kM);
        attn_kernel<<<96, 256, 0, stream>>>(qkvb, res_w + (size_t)l * 12 * 33, x);
        ln_kernel<<<kM, 256, 0, stream>>>(x, ffln_w + l * 768, ffln_b + l * 768, lnbuf);
        gemm_bt<2><<<dim3(6, 14), 256, 0, stream>>>(lnbuf, w1T + (size_t)l * 768 * 768, 768,
                                                    nullptr, b1 + l * 768, nullptr, gbuf, kM);
        gemm_bt<3><<<dim3(6, 14), 256, 0, stream>>>(gbuf, w2T + (size_t)l * 768 * 768, 768,
                                                    x, b2 + l * 768, nullptr, nullptr, kM);
    }
}

// Round 2
// 1074.219 us; speedup vs baseline: 1.4070x; 1.4070x over previous
//
#include <hip/hip_runtime.h>
#include <cstdint>
#include <cstddef>

typedef unsigned short u16;
typedef __bf16 bf16x8 __attribute__((ext_vector_type(8)));
typedef float f32x4 __attribute__((ext_vector_type(4)));

#define GLD16(gp, lp) __builtin_amdgcn_global_load_lds( \
    (const __attribute__((address_space(1))) void*)(gp), \
    (__attribute__((address_space(3))) void*)(lp), 16, 0, 0)

static constexpr int kNT  = 217;   // tokens per batch item
static constexpr int kM   = 1736;  // 8 * 217 valid rows
static constexpr int kMp  = 1792;  // padded
static constexpr int kSplit = 8;   // split-K for patch embed GEMM

__device__ __forceinline__ u16 f2bf(float f) {
    union { float f; unsigned u; } x; x.f = f;
    unsigned r = x.u + 0x7fffu + ((x.u >> 16) & 1u);
    return (u16)(r >> 16);
}

// ---------------- im2col: img (8,4,96,96,96) f32 -> A (1792 x 16384) bf16 -----
__global__ void im2col_kernel(const float* __restrict__ img, u16* __restrict__ A) {
    int t = blockIdx.x * 256 + threadIdx.x;
    int m  = t >> 10;
    int kb = t & 1023;
    int c = kb >> 8;
    int i = (kb >> 4) & 15;
    int j = kb & 15;
    int b = m / 216, p = m % 216;
    int pd = p / 36, ph = (p / 6) % 6, pw = p % 6;
    const float* src = img + ((((size_t)(b * 4 + c) * 96 + pd * 16 + i) * 96 + (ph * 16 + j)) * 96 + pw * 16);
    u16* dst = A + (size_t)m * 16384 + (size_t)kb * 16;
    #pragma unroll
    for (int q = 0; q < 16; q += 4) {
        float4 v = *(const float4*)(src + q);
        dst[q + 0] = f2bf(v.x); dst[q + 1] = f2bf(v.y);
        dst[q + 2] = f2bf(v.z); dst[q + 3] = f2bf(v.w);
    }
}

__global__ void cvt_kernel(const float* __restrict__ src, u16* __restrict__ dst) {
    size_t i = ((size_t)blockIdx.x * 256 + threadIdx.x) * 4;
    float4 v = *(const float4*)(src + i);
    dst[i + 0] = f2bf(v.x); dst[i + 1] = f2bf(v.y);
    dst[i + 2] = f2bf(v.z); dst[i + 3] = f2bf(v.w);
}

__global__ void transcvt(const float* __restrict__ src0, u16* __restrict__ dst0, int R, int C) {
    const float* src = src0 + (size_t)blockIdx.z * R * C;
    u16*         dst = dst0 + (size_t)blockIdx.z * R * C;
    __shared__ float tl[32][33];
    int c0 = blockIdx.x * 32, r0 = blockIdx.y * 32;
    for (int rr = threadIdx.y; rr < 32; rr += 8)
        tl[rr][threadIdx.x] = src[(size_t)(r0 + rr) * C + c0 + threadIdx.x];
    __syncthreads();
    for (int rr = threadIdx.y; rr < 32; rr += 8)
        dst[(size_t)(c0 + rr) * R + r0 + threadIdx.x] = f2bf(tl[threadIdx.x][rr]);
}

__global__ void token0_kernel(const float* __restrict__ clin, const float* __restrict__ ehr_w,
                              const float* __restrict__ ehr_b, const float* __restrict__ pos,
                              float* __restrict__ x) {
    int b = blockIdx.x;
    for (int o = threadIdx.x; o < 768; o += 256) {
        float acc = ehr_b[o] + pos[o];
        #pragma unroll
        for (int k = 0; k < 16; ++k) acc += clin[b * 16 + k] * ehr_w[k * 768 + o];
        x[(size_t)(b * kNT) * 768 + o] = acc;
    }
}

__global__ __launch_bounds__(256) void ln_kernel(const float* __restrict__ x,
                                                 const float* __restrict__ w,
                                                 const float* __restrict__ b,
                                                 u16* __restrict__ out) {
    int row = blockIdx.x;
    const float* xr = x + (size_t)row * 768;
    int tid = threadIdx.x;
    float v0 = xr[tid], v1 = xr[tid + 256], v2 = xr[tid + 512];
    float s = v0 + v1 + v2;
    float s2 = v0 * v0 + v1 * v1 + v2 * v2;
    #pragma unroll
    for (int o = 32; o; o >>= 1) { s += __shfl_xor(s, o); s2 += __shfl_xor(s2, o); }
    __shared__ float ps[4], ps2[4];
    int wave = tid >> 6, lane = tid & 63;
    if (lane == 0) { ps[wave] = s; ps2[wave] = s2; }
    __syncthreads();
    s = ps[0] + ps[1] + ps[2] + ps[3];
    s2 = ps2[0] + ps2[1] + ps2[2] + ps2[3];
    float mean = s * (1.0f / 768.0f);
    float var = s2 * (1.0f / 768.0f) - mean * mean;
    float rstd = rsqrtf(var + 1e-5f);
    u16* orow = out + (size_t)row * 768;
    orow[tid]       = f2bf((v0 - mean) * rstd * w[tid]       + b[tid]);
    orow[tid + 256] = f2bf((v1 - mean) * rstd * w[tid + 256] + b[tid + 256]);
    orow[tid + 512] = f2bf((v2 - mean) * rstd * w[tid + 512] + b[tid + 512]);
}

// ---------------- 128x128 MFMA GEMM w/ split-K, writes f32 partials ----------
// grid (N/128, M/128, kSplit); K-chunk = K/kSplit per z-block.
// LDS XOR-swizzle: row stride 32 u16 = 4x16B chunks; chunk ^= row&3.
__global__ void __launch_bounds__(256, 2)
gemm128_sk(const u16* __restrict__ A, const u16* __restrict__ B, int K,
           float* __restrict__ P, int Mvalid) {
    const int tid = threadIdx.x;
    const int lane = tid & 63;
    const int wave = tid >> 6;
    const int wm = wave >> 1, wn = wave & 1;
    const int bm = blockIdx.y * 128, bn = blockIdx.x * 128;
    const int kchunk = K / kSplit;
    const int kbeg = blockIdx.z * kchunk;

    __shared__ u16 As[128 * 32];
    __shared__ u16 Bs[128 * 32];

    f32x4 acc[4][4] = {};

    const int srow = tid >> 2;                     // 0..63
    const int schunk = (tid & 3) ^ (srow & 3);     // pre-swizzled source chunk
    const u16* Ag = A + (size_t)(bm + srow) * K + schunk * 8;
    const u16* Bg = B + (size_t)(bn + srow) * K + schunk * 8;
    u16* AsB = &As[tid * 8];
    u16* BsB = &Bs[tid * 8];
    const size_t rowStep = (size_t)64 * K;         // (srow+64)&3 == srow&3

    const int rl = lane & 15;
    const int cA = lane >> 4;                      // logical 16B chunk 0..3

    for (int k0 = kbeg; k0 < kbeg + kchunk; k0 += 32) {
        GLD16(Ag + k0, AsB);
        GLD16(Ag + k0 + rowStep, AsB + 2048);
        GLD16(Bg + k0, BsB);
        GLD16(Bg + k0 + rowStep, BsB + 2048);
        __syncthreads();
        bf16x8 af[4], bfr[4];
        #pragma unroll
        for (int i = 0; i < 4; ++i) {
            int r  = wm * 64 + i * 16 + rl;
            int rb = wn * 64 + i * 16 + rl;
            af[i]  = *(const bf16x8*)&As[r  * 32 + ((cA ^ (r  & 3)) << 3)];
            bfr[i] = *(const bf16x8*)&Bs[rb * 32 + ((cA ^ (rb & 3)) << 3)];
        }
        #pragma unroll
        for (int i = 0; i < 4; ++i)
            #pragma unroll
            for (int j = 0; j < 4; ++j)
                acc[i][j] = __builtin_amdgcn_mfma_f32_16x16x32_bf16(af[i], bfr[j], acc[i][j], 0, 0, 0);
        __syncthreads();
    }

    float* Pz = P + (size_t)blockIdx.z * Mvalid * 768;
    const int rl4 = (lane >> 4) * 4;
    const int cl = lane & 15;
    #pragma unroll
    for (int i = 0; i < 4; ++i)
        #pragma unroll
        for (int j = 0; j < 4; ++j) {
            const int col = bn + wn * 64 + j * 16 + cl;
            #pragma unroll
            for (int r = 0; r < 4; ++r) {
                const int row = bm + wm * 64 + i * 16 + rl4 + r;
                if (row < Mvalid) Pz[(size_t)row * 768 + col] = acc[i][j][r];
            }
        }
}

// ---------------- reduce split-K partials + conv_b + pos_emb -> x -------------
__global__ void reduce_patch(const float* __restrict__ P, const float* __restrict__ conv_b,
                             const float* __restrict__ pos, float* __restrict__ x) {
    int t = blockIdx.x * 256 + threadIdx.x;   // 1728*768/4 threads
    int idx = t * 4;
    int row = idx / 768;
    int col = idx % 768;
    float4 s = {0.f, 0.f, 0.f, 0.f};
    #pragma unroll
    for (int z = 0; z < kSplit; ++z) {
        float4 p = *(const float4*)(P + (size_t)z * 1728 * 768 + idx);
        s.x += p.x; s.y += p.y; s.z += p.z; s.w += p.w;
    }
    int b = row / 216, pp = row % 216;
    float4 cb = *(const float4*)(conv_b + col);
    float4 pe = *(const float4*)(pos + (size_t)(1 + pp) * 768 + col);
    float* o = x + (size_t)(b * kNT + 1 + pp) * 768 + col;
    o[0] = s.x + cb.x + pe.x; o[1] = s.y + cb.y + pe.y;
    o[2] = s.z + cb.z + pe.z; o[3] = s.w + cb.w + pe.w;
}

// ---------------- 64x64 MFMA GEMM for layer GEMMs (K=768) --------------------
// EPI 1: qkv -> Cf[row*2304+col] = v * (col<768 ? 0.125 : 1)
// EPI 2: ff1 -> Cb[row*768+col] = bf16(gelu(v + e0[col]))
// EPI 3: ff2 -> Cf[row*768+col] += v + e0[col]
template <int EPI>
__global__ void __launch_bounds__(256, 4)
gemm64(const u16* __restrict__ A, const u16* __restrict__ B, int K,
       float* __restrict__ Cf, const float* __restrict__ e0,
       u16* __restrict__ Cb, int Mvalid) {
    const int tid = threadIdx.x;
    const int lane = tid & 63;
    const int wave = tid >> 6;
    const int wm = wave >> 1, wn = wave & 1;
    const int bm = blockIdx.y * 64, bn = blockIdx.x * 64;

    __shared__ u16 As[64 * 64];
    __shared__ u16 Bs[64 * 64];

    f32x4 acc[2][2] = {};

    const int srow = tid >> 3;                    // 0..31
    const int schunk = (tid & 7) ^ (srow & 7);    // pre-swizzled source chunk
    const u16* Ag = A + (size_t)(bm + srow) * K + schunk * 8;
    const u16* Bg = B + (size_t)(bn + srow) * K + schunk * 8;
    u16* AsB = &As[tid * 8];
    u16* BsB = &Bs[tid * 8];
    const size_t rowStep = (size_t)32 * K;        // (srow+32)&7 == srow&7

    const int rl = lane & 15;
    const int kl = (lane >> 4) * 8;

    for (int k0 = 0; k0 < K; k0 += 64) {
        GLD16(Ag + k0, AsB);
        GLD16(Ag + k0 + rowStep, AsB + 2048);
        GLD16(Bg + k0, BsB);
        GLD16(Bg + k0 + rowStep, BsB + 2048);
        __syncthreads();
        #pragma unroll
        for (int kk = 0; kk < 64; kk += 32) {
            bf16x8 af[2], bfr[2];
            const int c = (kk + kl) >> 3;         // logical 16B chunk 0..7
            #pragma unroll
            for (int i = 0; i < 2; ++i) {
                int r  = wm * 32 + i * 16 + rl;
                int rb = wn * 32 + i * 16 + rl;
                af[i]  = *(const bf16x8*)&As[r  * 64 + ((c ^ (r  & 7)) << 3)];
                bfr[i] = *(const bf16x8*)&Bs[rb * 64 + ((c ^ (rb & 7)) << 3)];
            }
            #pragma unroll
            for (int i = 0; i < 2; ++i)
                #pragma unroll
                for (int j = 0; j < 2; ++j)
                    acc[i][j] = __builtin_amdgcn_mfma_f32_16x16x32_bf16(af[i], bfr[j], acc[i][j], 0, 0, 0);
        }
        __syncthreads();
    }

    const int rl4 = (lane >> 4) * 4;
    const int cl = lane & 15;
    #pragma unroll
    for (int i = 0; i < 2; ++i)
        #pragma unroll
        for (int j = 0; j < 2; ++j) {
            const int col = bn + wn * 32 + j * 16 + cl;
            #pragma unroll
            for (int r = 0; r < 4; ++r) {
                const int row = bm + wm * 32 + i * 16 + rl4 + r;
                if (row >= Mvalid) continue;
                float v = acc[i][j][r];
                if (EPI == 1) {
                    Cf[(size_t)row * 2304 + col] = (col < 768) ? v * 0.125f : v;
                } else if (EPI == 2) {
                    float t = v + e0[col];
                    float g = 0.5f * t * (1.0f + erff(t * 0.70710678118654752f));
                    Cb[(size_t)row * 768 + col] = f2bf(g);
                } else {
                    Cf[(size_t)row * 768 + col] += v + e0[col];
                }
            }
        }
}

// ---------------- attention (per (b,h)): token0 softmax + bcast + dwconv -----
__global__ __launch_bounds__(256) void attn_kernel(const float* __restrict__ qkv,
                                                   const float* __restrict__ resw_l,
                                                   float* __restrict__ x) {
    const int b = blockIdx.x / 12;
    const int h = blockIdx.x % 12;
    const int tid = threadIdx.x;
    const int wave = tid >> 6, lane = tid & 63;

    __shared__ float vs[217 * 64];
    __shared__ float sc[224];
    __shared__ float outp[64];
    __shared__ float rw[33];

    const size_t base = (size_t)(b * kNT) * 2304 + h * 64;

    for (int i = tid; i < 217 * 64; i += 256) {
        int n = i >> 6, d = i & 63;
        vs[i] = qkv[base + (size_t)n * 2304 + 1536 + d];
    }
    if (tid < 33) rw[tid] = resw_l[h * 33 + tid];

    float qp = qkv[base + lane];
    for (int j = wave; j < 217; j += 4) {
        float p = qp * qkv[base + (size_t)j * 2304 + 768 + lane];
        #pragma unroll
        for (int o = 32; o; o >>= 1) p += __shfl_xor(p, o);
        if (lane == 0) sc[j] = p;
    }
    __syncthreads();

    if (wave == 0) {
        float sv[4], e[4];
        float m = -1e30f;
        #pragma unroll
        for (int q = 0; q < 4; ++q) {
            int j = lane + q * 64;
            sv[q] = (j < 217) ? sc[j] : -1e30f;
            m = fmaxf(m, sv[q]);
        }
        #pragma unroll
        for (int o = 32; o; o >>= 1) m = fmaxf(m, __shfl_xor(m, o));
        float s = 0.0f;
        #pragma unroll
        for (int q = 0; q < 4; ++q) {
            int j = lane + q * 64;
            e[q] = (j < 217) ? expf(sv[q] - m) : 0.0f;
            s += e[q];
        }
        #pragma unroll
        for (int o = 32; o; o >>= 1) s += __shfl_xor(s, o);
        float inv = 1.0f / s;
        #pragma unroll
        for (int q = 0; q < 4; ++q) {
            int j = lane + q * 64;
            if (j < 217) sc[j] = e[q] * inv;
        }
    }
    __syncthreads();
    if (wave == 0) {
        float acc = 0.0f;
        for (int j = 0; j < 217; ++j) acc += sc[j] * vs[j * 64 + lane];
        outp[lane] = acc;
    }
    __syncthreads();

    const size_t xbase = (size_t)(b * kNT) * 768 + h * 64;
    for (int i = tid; i < 217 * 64; i += 256) {
        int n = i >> 6, d = i & 63;
        float bv = (n == 0) ? outp[d] : vs[d];
        float r = 0.0f;
        #pragma unroll
        for (int t = 0; t < 33; ++t) {
            int idx = n + t - 16;
            if (idx >= 0 && idx < 217) r += rw[t] * vs[idx * 64 + d];
        }
        x[xbase + (size_t)n * 768 + d] += bv + r;
    }
}

extern "C" void kernel_launch(void* const* d_in, const int* in_sizes, int n_in,
                              void* d_out, int out_size, void* d_ws, size_t ws_size,
                              hipStream_t stream) {
    const float* img    = (const float*)d_in[0];
    const float* clin   = (const float*)d_in[1];
    const float* conv_w = (const float*)d_in[2];
    const float* conv_b = (const float*)d_in[3];
    const float* ehr_w  = (const float*)d_in[4];
    const float* ehr_b  = (const float*)d_in[5];
    const float* pos    = (const float*)d_in[6];
    const float* ln_w   = (const float*)d_in[7];
    const float* ln_b   = (const float*)d_in[8];
    const float* qkv_w  = (const float*)d_in[9];
    const float* res_w  = (const float*)d_in[10];
    const float* ffln_w = (const float*)d_in[11];
    const float* ffln_b = (const float*)d_in[12];
    const float* w1     = (const float*)d_in[13];
    const float* b1     = (const float*)d_in[14];
    const float* w2     = (const float*)d_in[15];
    const float* b2     = (const float*)d_in[16];
    float* x = (float*)d_out;   // activations live directly in d_out (8*217*768 f32)

    char* ws = (char*)d_ws;
    u16* A_im  = (u16*)ws;  ws += (size_t)kMp * 16384 * 2;        // 58.7 MB
    u16* Bconv = (u16*)ws;  ws += (size_t)768 * 16384 * 2;        // 25.2 MB
    u16* qkvT  = (u16*)ws;  ws += (size_t)4 * 2304 * 768 * 2;     // 14.2 MB
    u16* w1T   = (u16*)ws;  ws += (size_t)4 * 768 * 768 * 2;      //  4.7 MB
    u16* w2T   = (u16*)ws;  ws += (size_t)4 * 768 * 768 * 2;      //  4.7 MB
    u16* lnbuf = (u16*)ws;  ws += (size_t)kMp * 768 * 2;          //  2.8 MB
    u16* gbuf  = (u16*)ws;  ws += (size_t)kMp * 768 * 2;          //  2.8 MB
    float* qkvb = (float*)ws;  ws += (size_t)kMp * 2304 * 4;      // 16.5 MB
    float* Pbuf = (float*)ws;  ws += (size_t)kSplit * 1728 * 768 * 4; // 40.5 MB

    im2col_kernel<<<6912, 256, 0, stream>>>(img, A_im);
    cvt_kernel<<<12288, 256, 0, stream>>>(conv_w, Bconv);
    transcvt<<<dim3(72, 24, 4), dim3(32, 8), 0, stream>>>(qkv_w, qkvT, 768, 2304);
    transcvt<<<dim3(24, 24, 4), dim3(32, 8), 0, stream>>>(w1, w1T, 768, 768);
    transcvt<<<dim3(24, 24, 4), dim3(32, 8), 0, stream>>>(w2, w2T, 768, 768);
    token0_kernel<<<8, 256, 0, stream>>>(clin, ehr_w, ehr_b, pos, x);
    gemm128_sk<<<dim3(6, 14, kSplit), 256, 0, stream>>>(A_im, Bconv, 16384, Pbuf, 1728);
    reduce_patch<<<1296, 256, 0, stream>>>(Pbuf, conv_b, pos, x);

    for (int l = 0; l < 4; ++l) {
        ln_kernel<<<kM, 256, 0, stream>>>(x, ln_w + l * 768, ln_b + l * 768, lnbuf);
        gemm64<1><<<dim3(36, 28), 256, 0, stream>>>(lnbuf, qkvT + (size_t)l * 2304 * 768, 768,
                                                    qkvb, nullptr, nullptr, kM);
        attn_kernel<<<96, 256, 0, stream>>>(qkvb, res_w + (size_t)l * 12 * 33, x);
        ln_kernel<<<kM, 256, 0, stream>>>(x, ffln_w + l * 768, ffln_b + l * 768, lnbuf);
        gemm64<2><<<dim3(12, 28), 256, 0, stream>>>(lnbuf, w1T + (size_t)l * 768 * 768, 768,
                                                    nullptr, b1 + l * 768, gbuf, kM);
        gemm64<3><<<dim3(12, 28), 256, 0, stream>>>(gbuf, w2T + (size_t)l * 768 * 768, 768,
                                                    x, b2 + l * 768, nullptr, kM);
    }
}

// Round 7
// 802.323 us; speedup vs baseline: 1.8839x; 1.3389x over previous
//
#include <hip/hip_runtime.h>
#include <cstdint>
#include <cstddef>

typedef unsigned short u16;
typedef __bf16 bf16x8 __attribute__((ext_vector_type(8)));
typedef float f32x4 __attribute__((ext_vector_type(4)));

#define GLD16(gp, lp) __builtin_amdgcn_global_load_lds( \
    (const __attribute__((address_space(1))) void*)(gp), \
    (__attribute__((address_space(3))) void*)(lp), 16, 0, 0)

static constexpr int kNT  = 217;   // tokens per batch item
static constexpr int kM   = 1736;  // 8 * 217 valid rows
static constexpr int kMp  = 1792;  // padded
static constexpr int kSplit = 8;   // split-K for patch embed GEMM

__device__ __forceinline__ u16 f2bf(float f) {
    union { float f; unsigned u; } x; x.f = f;
    unsigned r = x.u + 0x7fffu + ((x.u >> 16) & 1u);
    return (u16)(r >> 16);
}

// ---------------- im2col: img (8,4,96,96,96) f32 -> A (1792 x 16384) bf16 -----
__global__ void im2col_kernel(const float* __restrict__ img, u16* __restrict__ A) {
    int t = blockIdx.x * 256 + threadIdx.x;
    int m  = t >> 10;
    int kb = t & 1023;
    int c = kb >> 8;
    int i = (kb >> 4) & 15;
    int j = kb & 15;
    int b = m / 216, p = m % 216;
    int pd = p / 36, ph = (p / 6) % 6, pw = p % 6;
    const float* src = img + ((((size_t)(b * 4 + c) * 96 + pd * 16 + i) * 96 + (ph * 16 + j)) * 96 + pw * 16);
    u16* dst = A + (size_t)m * 16384 + (size_t)kb * 16;
    #pragma unroll
    for (int q = 0; q < 16; q += 4) {
        float4 v = *(const float4*)(src + q);
        dst[q + 0] = f2bf(v.x); dst[q + 1] = f2bf(v.y);
        dst[q + 2] = f2bf(v.z); dst[q + 3] = f2bf(v.w);
    }
}

__global__ void cvt_kernel(const float* __restrict__ src, u16* __restrict__ dst) {
    size_t i = ((size_t)blockIdx.x * 256 + threadIdx.x) * 4;
    float4 v = *(const float4*)(src + i);
    dst[i + 0] = f2bf(v.x); dst[i + 1] = f2bf(v.y);
    dst[i + 2] = f2bf(v.z); dst[i + 3] = f2bf(v.w);
}

__global__ void transcvt(const float* __restrict__ src0, u16* __restrict__ dst0, int R, int C) {
    const float* src = src0 + (size_t)blockIdx.z * R * C;
    u16*         dst = dst0 + (size_t)blockIdx.z * R * C;
    __shared__ float tl[32][33];
    int c0 = blockIdx.x * 32, r0 = blockIdx.y * 32;
    for (int rr = threadIdx.y; rr < 32; rr += 8)
        tl[rr][threadIdx.x] = src[(size_t)(r0 + rr) * C + c0 + threadIdx.x];
    __syncthreads();
    for (int rr = threadIdx.y; rr < 32; rr += 8)
        dst[(size_t)(c0 + rr) * R + r0 + threadIdx.x] = f2bf(tl[threadIdx.x][rr]);
}

__global__ void token0_kernel(const float* __restrict__ clin, const float* __restrict__ ehr_w,
                              const float* __restrict__ ehr_b, const float* __restrict__ pos,
                              float* __restrict__ x) {
    int b = blockIdx.x;
    for (int o = threadIdx.x; o < 768; o += 256) {
        float acc = ehr_b[o] + pos[o];
        #pragma unroll
        for (int k = 0; k < 16; ++k) acc += clin[b * 16 + k] * ehr_w[k * 768 + o];
        x[(size_t)(b * kNT) * 768 + o] = acc;
    }
}

__global__ __launch_bounds__(256) void ln_kernel(const float* __restrict__ x,
                                                 const float* __restrict__ w,
                                                 const float* __restrict__ b,
                                                 u16* __restrict__ out) {
    int row = blockIdx.x;
    const float* xr = x + (size_t)row * 768;
    int tid = threadIdx.x;
    float v0 = xr[tid], v1 = xr[tid + 256], v2 = xr[tid + 512];
    float s = v0 + v1 + v2;
    float s2 = v0 * v0 + v1 * v1 + v2 * v2;
    #pragma unroll
    for (int o = 32; o; o >>= 1) { s += __shfl_xor(s, o); s2 += __shfl_xor(s2, o); }
    __shared__ float ps[4], ps2[4];
    int wave = tid >> 6, lane = tid & 63;
    if (lane == 0) { ps[wave] = s; ps2[wave] = s2; }
    __syncthreads();
    s = ps[0] + ps[1] + ps[2] + ps[3];
    s2 = ps2[0] + ps2[1] + ps2[2] + ps2[3];
    float mean = s * (1.0f / 768.0f);
    float var = s2 * (1.0f / 768.0f) - mean * mean;
    float rstd = rsqrtf(var + 1e-5f);
    u16* orow = out + (size_t)row * 768;
    orow[tid]       = f2bf((v0 - mean) * rstd * w[tid]       + b[tid]);
    orow[tid + 256] = f2bf((v1 - mean) * rstd * w[tid + 256] + b[tid + 256]);
    orow[tid + 512] = f2bf((v2 - mean) * rstd * w[tid + 512] + b[tid + 512]);
}

// ---------------- 128x128 MFMA GEMM w/ split-K, writes f32 partials ----------
__global__ void __launch_bounds__(256, 2)
gemm128_sk(const u16* __restrict__ A, const u16* __restrict__ B, int K,
           float* __restrict__ P, int Mvalid) {
    const int tid = threadIdx.x;
    const int lane = tid & 63;
    const int wave = tid >> 6;
    const int wm = wave >> 1, wn = wave & 1;
    const int bm = blockIdx.y * 128, bn = blockIdx.x * 128;
    const int kchunk = K / kSplit;
    const int kbeg = blockIdx.z * kchunk;

    __shared__ u16 As[128 * 32];
    __shared__ u16 Bs[128 * 32];

    f32x4 acc[4][4] = {};

    const int srow = tid >> 2;
    const int schunk = (tid & 3) ^ (srow & 3);
    const u16* Ag = A + (size_t)(bm + srow) * K + schunk * 8;
    const u16* Bg = B + (size_t)(bn + srow) * K + schunk * 8;
    u16* AsB = &As[tid * 8];
    u16* BsB = &Bs[tid * 8];
    const size_t rowStep = (size_t)64 * K;

    const int rl = lane & 15;
    const int cA = lane >> 4;

    for (int k0 = kbeg; k0 < kbeg + kchunk; k0 += 32) {
        GLD16(Ag + k0, AsB);
        GLD16(Ag + k0 + rowStep, AsB + 2048);
        GLD16(Bg + k0, BsB);
        GLD16(Bg + k0 + rowStep, BsB + 2048);
        __syncthreads();
        bf16x8 af[4], bfr[4];
        #pragma unroll
        for (int i = 0; i < 4; ++i) {
            int r  = wm * 64 + i * 16 + rl;
            int rb = wn * 64 + i * 16 + rl;
            af[i]  = *(const bf16x8*)&As[r  * 32 + ((cA ^ (r  & 3)) << 3)];
            bfr[i] = *(const bf16x8*)&Bs[rb * 32 + ((cA ^ (rb & 3)) << 3)];
        }
        #pragma unroll
        for (int i = 0; i < 4; ++i)
            #pragma unroll
            for (int j = 0; j < 4; ++j)
                acc[i][j] = __builtin_amdgcn_mfma_f32_16x16x32_bf16(af[i], bfr[j], acc[i][j], 0, 0, 0);
        __syncthreads();
    }

    float* Pz = P + (size_t)blockIdx.z * Mvalid * 768;
    const int rl4 = (lane >> 4) * 4;
    const int cl = lane & 15;
    #pragma unroll
    for (int i = 0; i < 4; ++i)
        #pragma unroll
        for (int j = 0; j < 4; ++j) {
            const int col = bn + wn * 64 + j * 16 + cl;
            #pragma unroll
            for (int r = 0; r < 4; ++r) {
                const int row = bm + wm * 64 + i * 16 + rl4 + r;
                if (row < Mvalid) Pz[(size_t)row * 768 + col] = acc[i][j][r];
            }
        }
}

// ---------------- reduce split-K partials + conv_b + pos_emb -> x -------------
__global__ void reduce_patch(const float* __restrict__ P, const float* __restrict__ conv_b,
                             const float* __restrict__ pos, float* __restrict__ x) {
    int t = blockIdx.x * 256 + threadIdx.x;
    int idx = t * 4;
    int row = idx / 768;
    int col = idx % 768;
    float4 s = {0.f, 0.f, 0.f, 0.f};
    #pragma unroll
    for (int z = 0; z < kSplit; ++z) {
        float4 p = *(const float4*)(P + (size_t)z * 1728 * 768 + idx);
        s.x += p.x; s.y += p.y; s.z += p.z; s.w += p.w;
    }
    int b = row / 216, pp = row % 216;
    float4 cb = *(const float4*)(conv_b + col);
    float4 pe = *(const float4*)(pos + (size_t)(1 + pp) * 768 + col);
    float* o = x + (size_t)(b * kNT + 1 + pp) * 768 + col;
    o[0] = s.x + cb.x + pe.x; o[1] = s.y + cb.y + pe.y;
    o[2] = s.z + cb.z + pe.z; o[3] = s.w + cb.w + pe.w;
}

// ---------------- 64x64 MFMA GEMM for layer GEMMs (K=768) --------------------
template <int EPI>
__global__ void __launch_bounds__(256, 4)
gemm64(const u16* __restrict__ A, const u16* __restrict__ B, int K,
       float* __restrict__ Cf, const float* __restrict__ e0,
       u16* __restrict__ Cb, int Mvalid) {
    const int tid = threadIdx.x;
    const int lane = tid & 63;
    const int wave = tid >> 6;
    const int wm = wave >> 1, wn = wave & 1;
    const int bm = blockIdx.y * 64, bn = blockIdx.x * 64;

    __shared__ u16 As[64 * 64];
    __shared__ u16 Bs[64 * 64];

    f32x4 acc[2][2] = {};

    const int srow = tid >> 3;
    const int schunk = (tid & 7) ^ (srow & 7);
    const u16* Ag = A + (size_t)(bm + srow) * K + schunk * 8;
    const u16* Bg = B + (size_t)(bn + srow) * K + schunk * 8;
    u16* AsB = &As[tid * 8];
    u16* BsB = &Bs[tid * 8];
    const size_t rowStep = (size_t)32 * K;

    const int rl = lane & 15;
    const int kl = (lane >> 4) * 8;

    for (int k0 = 0; k0 < K; k0 += 64) {
        GLD16(Ag + k0, AsB);
        GLD16(Ag + k0 + rowStep, AsB + 2048);
        GLD16(Bg + k0, BsB);
        GLD16(Bg + k0 + rowStep, BsB + 2048);
        __syncthreads();
        #pragma unroll
        for (int kk = 0; kk < 64; kk += 32) {
            bf16x8 af[2], bfr[2];
            const int c = (kk + kl) >> 3;
            #pragma unroll
            for (int i = 0; i < 2; ++i) {
                int r  = wm * 32 + i * 16 + rl;
                int rb = wn * 32 + i * 16 + rl;
                af[i]  = *(const bf16x8*)&As[r  * 64 + ((c ^ (r  & 7)) << 3)];
                bfr[i] = *(const bf16x8*)&Bs[rb * 64 + ((c ^ (rb & 7)) << 3)];
            }
            #pragma unroll
            for (int i = 0; i < 2; ++i)
                #pragma unroll
                for (int j = 0; j < 2; ++j)
                    acc[i][j] = __builtin_amdgcn_mfma_f32_16x16x32_bf16(af[i], bfr[j], acc[i][j], 0, 0, 0);
        }
        __syncthreads();
    }

    const int rl4 = (lane >> 4) * 4;
    const int cl = lane & 15;
    #pragma unroll
    for (int i = 0; i < 2; ++i)
        #pragma unroll
        for (int j = 0; j < 2; ++j) {
            const int col = bn + wn * 32 + j * 16 + cl;
            #pragma unroll
            for (int r = 0; r < 4; ++r) {
                const int row = bm + wm * 32 + i * 16 + rl4 + r;
                if (row >= Mvalid) continue;
                float v = acc[i][j][r];
                if (EPI == 1) {
                    Cf[(size_t)row * 2304 + col] = (col < 768) ? v * 0.125f : v;
                } else if (EPI == 2) {
                    float t = v + e0[col];
                    float g = 0.5f * t * (1.0f + erff(t * 0.70710678118654752f));
                    Cb[(size_t)row * 768 + col] = f2bf(g);
                } else {
                    Cf[(size_t)row * 768 + col] += v + e0[col];
                }
            }
        }
}

// ---------------- attn part 1: token0 scores + softmax + weighted V ----------
// one block per (b,h); all 4 waves share the dot products and the V-sum.
__global__ __launch_bounds__(256) void attn_scores(const float* __restrict__ qkv,
                                                   float* __restrict__ obuf) {
    const int b = blockIdx.x / 12;
    const int h = blockIdx.x % 12;
    const int tid = threadIdx.x;
    const int wave = tid >> 6, lane = tid & 63;

    __shared__ float sc[224];
    __shared__ float part[4][64];

    const size_t base = (size_t)(b * kNT) * 2304 + h * 64;

    // scores s_j = qp . k_j  (qp already scaled by 1/8 in gemm epilogue)
    float qp = qkv[base + lane];
    for (int j = wave; j < 217; j += 4) {
        float p = qp * qkv[base + (size_t)j * 2304 + 768 + lane];
        #pragma unroll
        for (int o = 32; o; o >>= 1) p += __shfl_xor(p, o);
        if (lane == 0) sc[j] = p;
    }
    __syncthreads();

    if (wave == 0) {
        float sv[4], e[4];
        float m = -1e30f;
        #pragma unroll
        for (int q = 0; q < 4; ++q) {
            int j = lane + q * 64;
            sv[q] = (j < 217) ? sc[j] : -1e30f;
            m = fmaxf(m, sv[q]);
        }
        #pragma unroll
        for (int o = 32; o; o >>= 1) m = fmaxf(m, __shfl_xor(m, o));
        float s = 0.0f;
        #pragma unroll
        for (int q = 0; q < 4; ++q) {
            int j = lane + q * 64;
            e[q] = (j < 217) ? expf(sv[q] - m) : 0.0f;
            s += e[q];
        }
        #pragma unroll
        for (int o = 32; o; o >>= 1) s += __shfl_xor(s, o);
        float inv = 1.0f / s;
        #pragma unroll
        for (int q = 0; q < 4; ++q) {
            int j = lane + q * 64;
            if (j < 217) sc[j] = e[q] * inv;
        }
    }
    __syncthreads();

    // weighted V sum split over the 4 waves
    float acc = 0.0f;
    for (int j = wave; j < 217; j += 4)
        acc += sc[j] * qkv[base + (size_t)j * 2304 + 1536 + lane];
    part[wave][lane] = acc;
    __syncthreads();
    if (wave == 0)
        obuf[(size_t)blockIdx.x * 64 + lane] =
            part[0][lane] + part[1][lane] + part[2][lane] + part[3][lane];
}

// ---------------- attn part 2: broadcast + depthwise 33-tap conv + add -------
// grid (7 token-chunks, 12 heads, 8 batch); 32 tokens per block.
__global__ __launch_bounds__(256) void attn_apply(const float* __restrict__ qkv,
                                                  const float* __restrict__ resw_l,
                                                  const float* __restrict__ obuf,
                                                  float* __restrict__ x) {
    const int b = blockIdx.z, h = blockIdx.y;
    const int n0 = blockIdx.x * 32;
    const int tid = threadIdx.x;
    const int d = tid & 63, nl = tid >> 6;

    __shared__ float Vl[64 * 64];   // tokens n0-16 .. n0+47, zero-padded
    __shared__ float rw[33];
    __shared__ float bcv[64];       // v token0

    const size_t vbase = (size_t)(b * kNT) * 2304 + h * 64 + 1536;
    for (int i = tid; i < 4096; i += 256) {
        int row = i >> 6, dd = i & 63;
        int tok = n0 - 16 + row;
        Vl[i] = (tok >= 0 && tok < kNT) ? qkv[vbase + (size_t)tok * 2304 + dd] : 0.0f;
    }
    if (tid < 33) rw[tid] = resw_l[h * 33 + tid];
    if (tid < 64) bcv[tid] = qkv[vbase + tid];
    __syncthreads();

    const float ob = obuf[(size_t)(b * 12 + h) * 64 + d];
    float* xp = x + (size_t)(b * kNT) * 768 + h * 64 + d;
    #pragma unroll
    for (int q = 0; q < 8; ++q) {
        int n = n0 + nl + q * 4;
        if (n >= kNT) continue;
        float r = 0.0f;
        #pragma unroll
        for (int t = 0; t < 33; ++t)
            r += rw[t] * Vl[(n - n0 + t) * 64 + d];
        float bv = (n == 0) ? ob : bcv[d];
        xp[(size_t)n * 768] += bv + r;
    }
}

extern "C" void kernel_launch(void* const* d_in, const int* in_sizes, int n_in,
                              void* d_out, int out_size, void* d_ws, size_t ws_size,
                              hipStream_t stream) {
    const float* img    = (const float*)d_in[0];
    const float* clin   = (const float*)d_in[1];
    const float* conv_w = (const float*)d_in[2];
    const float* conv_b = (const float*)d_in[3];
    const float* ehr_w  = (const float*)d_in[4];
    const float* ehr_b  = (const float*)d_in[5];
    const float* pos    = (const float*)d_in[6];
    const float* ln_w   = (const float*)d_in[7];
    const float* ln_b   = (const float*)d_in[8];
    const float* qkv_w  = (const float*)d_in[9];
    const float* res_w  = (const float*)d_in[10];
    const float* ffln_w = (const float*)d_in[11];
    const float* ffln_b = (const float*)d_in[12];
    const float* w1     = (const float*)d_in[13];
    const float* b1     = (const float*)d_in[14];
    const float* w2     = (const float*)d_in[15];
    const float* b2     = (const float*)d_in[16];
    float* x = (float*)d_out;

    char* ws = (char*)d_ws;
    u16* A_im  = (u16*)ws;  ws += (size_t)kMp * 16384 * 2;
    u16* Bconv = (u16*)ws;  ws += (size_t)768 * 16384 * 2;
    u16* qkvT  = (u16*)ws;  ws += (size_t)4 * 2304 * 768 * 2;
    u16* w1T   = (u16*)ws;  ws += (size_t)4 * 768 * 768 * 2;
    u16* w2T   = (u16*)ws;  ws += (size_t)4 * 768 * 768 * 2;
    u16* lnbuf = (u16*)ws;  ws += (size_t)kMp * 768 * 2;
    u16* gbuf  = (u16*)ws;  ws += (size_t)kMp * 768 * 2;
    float* qkvb = (float*)ws;  ws += (size_t)kMp * 2304 * 4;
    float* Pbuf = (float*)ws;  ws += (size_t)kSplit * 1728 * 768 * 4;
    float* obuf = (float*)ws;  ws += (size_t)96 * 64 * 4;

    im2col_kernel<<<6912, 256, 0, stream>>>(img, A_im);
    cvt_kernel<<<12288, 256, 0, stream>>>(conv_w, Bconv);
    transcvt<<<dim3(72, 24, 4), dim3(32, 8), 0, stream>>>(qkv_w, qkvT, 768, 2304);
    transcvt<<<dim3(24, 24, 4), dim3(32, 8), 0, stream>>>(w1, w1T, 768, 768);
    transcvt<<<dim3(24, 24, 4), dim3(32, 8), 0, stream>>>(w2, w2T, 768, 768);
    token0_kernel<<<8, 256, 0, stream>>>(clin, ehr_w, ehr_b, pos, x);
    gemm128_sk<<<dim3(6, 14, kSplit), 256, 0, stream>>>(A_im, Bconv, 16384, Pbuf, 1728);
    reduce_patch<<<1296, 256, 0, stream>>>(Pbuf, conv_b, pos, x);

    for (int l = 0; l < 4; ++l) {
        ln_kernel<<<kM, 256, 0, stream>>>(x, ln_w + l * 768, ln_b + l * 768, lnbuf);
        gemm64<1><<<dim3(36, 28), 256, 0, stream>>>(lnbuf, qkvT + (size_t)l * 2304 * 768, 768,
                                                    qkvb, nullptr, nullptr, kM);
        attn_scores<<<96, 256, 0, stream>>>(qkvb, obuf);
        attn_apply<<<dim3(7, 12, 8), 256, 0, stream>>>(qkvb, res_w + (size_t)l * 12 * 33, obuf, x);
        ln_kernel<<<kM, 256, 0, stream>>>(x, ffln_w + l * 768, ffln_b + l * 768, lnbuf);
        gemm64<2><<<dim3(12, 28), 256, 0, stream>>>(lnbuf, w1T + (size_t)l * 768 * 768, 768,
                                                    nullptr, b1 + l * 768, gbuf, kM);
        gemm64<3><<<dim3(12, 28), 256, 0, stream>>>(gbuf, w2T + (size_t)l * 768 * 768, 768,
                                                    x, b2 + l * 768, nullptr, kM);
    }
}